// Round 1
// baseline (259.525 us; speedup 1.0000x reference)
//
#include <hip/hip_runtime.h>

// TSM (temporal shift): x (128,96,56,56) f32 viewed as (16,8,96,56,56).
//   c in [0,32):  out[b,t] = x[b,t+1]  (zero at t=7)   -- shift "past<-future"
//   c in [32,64): out[b,t] = x[b,t-1]  (zero at t=0)   -- shift "future<-past"
//   c in [64,96): out[b,t] = x[b,t]
// Pure plane-permutation: each (b,t,c) HW-plane (3136 f32 = 784 float4,
// 16B-aligned since 12544 % 16 == 0) is copied from one source plane or
// zero-filled. One block per plane; (t,c) logic is block-uniform scalar.

#define C_TOT   96
#define FOLD    32
#define NFRAME  8
#define HW4     784   // 56*56/4 float4 per plane
#define NPLANES 12288 // 128*96

__global__ __launch_bounds__(256) void tsm_kernel(const float4* __restrict__ in,
                                                  float4* __restrict__ out) {
    const int plane = blockIdx.x;              // b*768 + t*96 + c
    const int c = plane % C_TOT;
    const int t = (plane / C_TOT) % NFRAME;

    int  delta = 0;
    bool zero  = false;
    if (c < FOLD)          { delta =  C_TOT; zero = (t == NFRAME - 1); }
    else if (c < 2 * FOLD) { delta = -C_TOT; zero = (t == 0); }

    const long base = (long)plane * HW4;
    float4* o = out + base;

    if (zero) {
        const float4 z = make_float4(0.f, 0.f, 0.f, 0.f);
        #pragma unroll
        for (int j = threadIdx.x; j < HW4; j += 256) o[j] = z;
    } else {
        const float4* s = in + base + (long)delta * HW4;
        #pragma unroll
        for (int j = threadIdx.x; j < HW4; j += 256) o[j] = s[j];
    }
}

extern "C" void kernel_launch(void* const* d_in, const int* in_sizes, int n_in,
                              void* d_out, int out_size, void* d_ws, size_t ws_size,
                              hipStream_t stream) {
    const float4* x   = (const float4*)d_in[0];
    float4*       out = (float4*)d_out;
    tsm_kernel<<<NPLANES, 256, 0, stream>>>(x, out);
}

// Round 2
// 246.179 us; speedup vs baseline: 1.0542x; 1.0542x over previous
//
#include <hip/hip_runtime.h>

// TSM (temporal shift): x (128,96,56,56) f32 viewed as (16,8,96,56,56).
//   c in [0,32):  out[b,t] = x[b,t+1]  (zero at t=7)
//   c in [32,64): out[b,t] = x[b,t-1]  (zero at t=0)
//   c in [64,96): out[b,t] = x[b,t]
// Pure plane permutation; one block per 56x56 plane (784 float4 = 12544 B).
// R2: batch loads before stores (MLP) + nontemporal hints (zero-reuse stream,
// every input plane read exactly once, output written exactly once).

#define C_TOT   96
#define FOLD    32
#define NFRAME  8
#define HW4     784   // 56*56/4 float4 per plane
#define NPLANES 12288 // 128*96

typedef float v4f __attribute__((ext_vector_type(4)));

__global__ __launch_bounds__(256) void tsm_kernel(const v4f* __restrict__ in,
                                                  v4f* __restrict__ out) {
    const int plane = blockIdx.x;              // b*768 + t*96 + c
    const int c = plane % C_TOT;
    const int t = (plane / C_TOT) % NFRAME;

    int  delta = 0;                            // block-uniform scalars
    bool zero  = false;
    if (c < FOLD)          { delta =  C_TOT; zero = (t == NFRAME - 1); }
    else if (c < 2 * FOLD) { delta = -C_TOT; zero = (t == 0); }

    const long base = (long)plane * HW4;
    v4f* o = out + base;
    const int j = threadIdx.x;                 // 784 = 3*256 + 16

    if (zero) {
        const v4f z = (v4f){0.f, 0.f, 0.f, 0.f};
        __builtin_nontemporal_store(z, &o[j]);
        __builtin_nontemporal_store(z, &o[j + 256]);
        __builtin_nontemporal_store(z, &o[j + 512]);
        if (j < HW4 - 768) __builtin_nontemporal_store(z, &o[j + 768]);
    } else {
        const v4f* s = in + base + (long)delta * HW4;
        v4f a0 = __builtin_nontemporal_load(&s[j]);
        v4f a1 = __builtin_nontemporal_load(&s[j + 256]);
        v4f a2 = __builtin_nontemporal_load(&s[j + 512]);
        v4f a3;
        const bool tail = (j < HW4 - 768);
        if (tail) a3 = __builtin_nontemporal_load(&s[j + 768]);
        __builtin_nontemporal_store(a0, &o[j]);
        __builtin_nontemporal_store(a1, &o[j + 256]);
        __builtin_nontemporal_store(a2, &o[j + 512]);
        if (tail) __builtin_nontemporal_store(a3, &o[j + 768]);
    }
}

extern "C" void kernel_launch(void* const* d_in, const int* in_sizes, int n_in,
                              void* d_out, int out_size, void* d_ws, size_t ws_size,
                              hipStream_t stream) {
    const v4f* x   = (const v4f*)d_in[0];
    v4f*       out = (v4f*)d_out;
    tsm_kernel<<<NPLANES, 256, 0, stream>>>(x, out);
}